// Round 1
// baseline (372.507 us; speedup 1.0000x reference)
//
#include <hip/hip_runtime.h>

#define BN 32768
#define IN 512
#define NE 8
#define NH 128
#define MO 256
#define NOUT 2

// ---------------- init: out[b,j] = bout[j] ----------------
__global__ void init_out_kernel(float* __restrict__ out, const float* __restrict__ bout) {
    int i = blockIdx.x * blockDim.x + threadIdx.x;
    if (i < BN * NOUT) out[i] = bout[i & 1];
}

// ---------------- gating: logits, top-2, bucketing ----------------
// wave-per-row, 8 rows per wave, 4 waves (32 rows) per block, 1024 blocks.
// f64 accumulation so top-2 selection matches the f64 np reference at near-ties.
__global__ __launch_bounds__(256) void gate_kernel(
    const float* __restrict__ x, const float* __restrict__ wg,
    int* __restrict__ gcount, int* __restrict__ gload, float* __restrict__ gimp,
    int* __restrict__ idx_list, float* __restrict__ gate_list)
{
    __shared__ int counts_s[NE];
    __shared__ int load_s[NE];
    __shared__ float imp_s[NE];
    __shared__ int base_s[NE];
    __shared__ int rec_e[64];
    __shared__ int rec_p[64];
    __shared__ float rec_g[64];

    int tid = threadIdx.x;
    if (tid < NE) { counts_s[tid] = 0; load_s[tid] = 0; imp_s[tid] = 0.f; }
    __syncthreads();

    int lane = tid & 63;
    int wave = tid >> 6;

    for (int t = 0; t < 8; ++t) {
        int row = blockIdx.x * 32 + wave * 8 + t;
        const float* xr = x + (size_t)row * IN;
        double acc[NE];
        #pragma unroll
        for (int e = 0; e < NE; ++e) acc[e] = 0.0;
        #pragma unroll
        for (int j = 0; j < 8; ++j) {
            int k = lane + 64 * j;
            double xv = (double)xr[k];
            const float4* w4 = (const float4*)(wg + (size_t)k * NE);
            float4 w0 = w4[0], w1 = w4[1];
            acc[0] += xv * (double)w0.x; acc[1] += xv * (double)w0.y;
            acc[2] += xv * (double)w0.z; acc[3] += xv * (double)w0.w;
            acc[4] += xv * (double)w1.x; acc[5] += xv * (double)w1.y;
            acc[6] += xv * (double)w1.z; acc[7] += xv * (double)w1.w;
        }
        #pragma unroll
        for (int m = 1; m < 64; m <<= 1) {
            #pragma unroll
            for (int e = 0; e < NE; ++e) acc[e] += __shfl_xor(acc[e], m, 64);
        }
        if (lane == 0) {
            int e0 = 0; double v0 = acc[0];
            #pragma unroll
            for (int e = 1; e < NE; ++e) if (acc[e] > v0) { v0 = acc[e]; e0 = e; }
            int e1 = (e0 == 0) ? 1 : 0; double v1 = acc[e1];
            #pragma unroll
            for (int e = 0; e < NE; ++e)
                if (e != e0 && acc[e] > v1) { v1 = acc[e]; e1 = e; }
            float t1 = expf((float)(v1 - v0));
            float s = 1.f + t1;
            float g0 = 1.f / s;
            float g1 = t1 / s;
            atomicAdd(&imp_s[e0], g0);
            atomicAdd(&imp_s[e1], g1);
            if (g0 > 0.f) atomicAdd(&load_s[e0], 1);
            if (g1 > 0.f) atomicAdd(&load_s[e1], 1);
            int p0 = atomicAdd(&counts_s[e0], 1);
            int p1 = atomicAdd(&counts_s[e1], 1);
            int rl = (wave * 8 + t) * 2;
            rec_e[rl] = e0; rec_e[rl + 1] = e1;
            rec_g[rl] = g0; rec_g[rl + 1] = g1;
            rec_p[rl] = p0; rec_p[rl + 1] = p1;
        }
    }
    __syncthreads();
    if (tid < NE) {
        base_s[tid] = atomicAdd(&gcount[tid], counts_s[tid]);
        atomicAdd(&gimp[tid], imp_s[tid]);
        atomicAdd(&gload[tid], load_s[tid]);
    }
    __syncthreads();
    if (tid < 64) {
        int e = rec_e[tid];
        int pos = base_s[e] + rec_p[tid];
        int row = blockIdx.x * 32 + (tid >> 1);
        idx_list[e * BN + pos] = row;
        gate_list[e * BN + pos] = rec_g[tid];
    }
}

// ---------------- loss ----------------
__global__ void loss_kernel(const float* __restrict__ gimp, const int* __restrict__ gload,
                            float* __restrict__ out) {
    if (threadIdx.x == 0 && blockIdx.x == 0) {
        float mi = 0.f, ml = 0.f;
        for (int e = 0; e < NE; ++e) { mi += gimp[e]; ml += (float)gload[e]; }
        mi *= 0.125f; ml *= 0.125f;
        float vi = 0.f, vl = 0.f;
        for (int e = 0; e < NE; ++e) {
            float d = gimp[e] - mi;  vi += d * d;
            float d2 = (float)gload[e] - ml; vl += d2 * d2;
        }
        vi *= (1.f / 7.f); vl *= (1.f / 7.f);
        float loss = (vi / (mi * mi + 1e-10f) + vl / (ml * ml + 1e-10f)) * 0.01f;
        out[BN * NOUT] = loss;
    }
}

// ---------------- expert compute: per (expert, 32-row tile) ----------------
// stage1: H[32x128] = relu(Xg[32x512] @ W1[e] + b1[e])   (micro-tile 4x4)
// stage2: Z[32x256] = H @ W2[e] + b2[e]                  (micro-tile 4x8)
// epilogue: out[b,:2] += g * softmax(Z) @ Wout           (fused, 2 atomics/row)
__global__ __launch_bounds__(256) void expert_kernel(
    const float* __restrict__ x,
    const float* __restrict__ W1, const float* __restrict__ b1,
    const float* __restrict__ W2, const float* __restrict__ b2,
    const float* __restrict__ Wout,
    const int* __restrict__ gcount,
    const int* __restrict__ idx_list, const float* __restrict__ gate_list,
    float* __restrict__ out)
{
    __shared__ __align__(16) union {
        struct { float xsT[32][36]; float ws1[32][128]; } s1; // 20992 B
        float w2s[16][256];                                   // 16384 B
    } sm;
    __shared__ __align__(16) float HT[128][36];               // 18432 B, HT[col][row]
    __shared__ int idx_s[32];
    __shared__ float gate_s[32];

    int e = blockIdx.y;
    int cnt = gcount[e];
    int row0 = blockIdx.x * 32;
    if (row0 >= cnt) return;
    int tid = threadIdx.x;

    if (tid < 32) {
        int gi = row0 + tid;
        int ok = gi < cnt;
        idx_s[tid]  = idx_list[e * BN + (ok ? gi : row0)];
        gate_s[tid] = ok ? gate_list[e * BN + gi] : 0.f;
    }
    __syncthreads();

    int tx = tid & 31;   // stage1 cols tx*4.., stage2 cols tx*8..
    int ty = tid >> 5;   // rows ty*4..ty*4+3

    // ---- stage 1 ----
    const float* W1e = W1 + (size_t)e * IN * NH;
    float c1[4][4];
    #pragma unroll
    for (int i = 0; i < 4; ++i)
        #pragma unroll
        for (int j = 0; j < 4; ++j) c1[i][j] = 0.f;

    for (int k0 = 0; k0 < IN; k0 += 32) {
        {   // gather X chunk (transposed store)
            int f4 = tid & 7, r = tid >> 3;
            const float* src = x + (size_t)idx_s[r] * IN + k0 + f4 * 4;
            float4 v = *(const float4*)src;
            sm.s1.xsT[f4 * 4 + 0][r] = v.x;
            sm.s1.xsT[f4 * 4 + 1][r] = v.y;
            sm.s1.xsT[f4 * 4 + 2][r] = v.z;
            sm.s1.xsT[f4 * 4 + 3][r] = v.w;
        }
        {   // W1 chunk
            int c4 = (tid & 31) * 4, kr = tid >> 5;
            #pragma unroll
            for (int p = 0; p < 4; ++p) {
                int k = kr + p * 8;
                *(float4*)&sm.s1.ws1[k][c4] = *(const float4*)(W1e + (size_t)(k0 + k) * NH + c4);
            }
        }
        __syncthreads();
        #pragma unroll
        for (int kk = 0; kk < 32; ++kk) {
            float4 av = *(const float4*)&sm.s1.xsT[kk][ty * 4];
            float4 bv = *(const float4*)&sm.s1.ws1[kk][tx * 4];
            float aa[4] = {av.x, av.y, av.z, av.w};
            float bb[4] = {bv.x, bv.y, bv.z, bv.w};
            #pragma unroll
            for (int i = 0; i < 4; ++i)
                #pragma unroll
                for (int j = 0; j < 4; ++j)
                    c1[i][j] = fmaf(aa[i], bb[j], c1[i][j]);
        }
        __syncthreads();
    }

    {   // relu + b1, store H transposed
        float4 b1v = *(const float4*)(b1 + e * NH + tx * 4);
        float bb[4] = {b1v.x, b1v.y, b1v.z, b1v.w};
        #pragma unroll
        for (int j = 0; j < 4; ++j) {
            float4 hv;
            hv.x = fmaxf(c1[0][j] + bb[j], 0.f);
            hv.y = fmaxf(c1[1][j] + bb[j], 0.f);
            hv.z = fmaxf(c1[2][j] + bb[j], 0.f);
            hv.w = fmaxf(c1[3][j] + bb[j], 0.f);
            *(float4*)&HT[tx * 4 + j][ty * 4] = hv;
        }
    }
    __syncthreads();

    // ---- stage 2 ----
    float z[4][8];
    #pragma unroll
    for (int i = 0; i < 4; ++i)
        #pragma unroll
        for (int j = 0; j < 8; ++j) z[i][j] = 0.f;

    const float* W2e = W2 + (size_t)e * NH * MO;
    for (int k0 = 0; k0 < NH; k0 += 16) {
        {
            int c4 = (tid & 63) * 4, kr = tid >> 6;
            #pragma unroll
            for (int p = 0; p < 4; ++p) {
                int k = kr + p * 4;
                *(float4*)&sm.w2s[k][c4] = *(const float4*)(W2e + (size_t)(k0 + k) * MO + c4);
            }
        }
        __syncthreads();
        #pragma unroll
        for (int kk = 0; kk < 16; ++kk) {
            float4 av = *(const float4*)&HT[k0 + kk][ty * 4];
            float4 b0 = *(const float4*)&sm.w2s[kk][tx * 8];
            float4 b1v = *(const float4*)&sm.w2s[kk][tx * 8 + 4];
            float aa[4] = {av.x, av.y, av.z, av.w};
            float bb[8] = {b0.x, b0.y, b0.z, b0.w, b1v.x, b1v.y, b1v.z, b1v.w};
            #pragma unroll
            for (int i = 0; i < 4; ++i)
                #pragma unroll
                for (int j = 0; j < 8; ++j)
                    z[i][j] = fmaf(aa[i], bb[j], z[i][j]);
        }
        __syncthreads();
    }

    // ---- epilogue: softmax over 256 (32 lanes x 8 cols), fuse @Wout ----
    float4 b2a = *(const float4*)(b2 + e * MO + tx * 8);
    float4 b2b = *(const float4*)(b2 + e * MO + tx * 8 + 4);
    float bz[8] = {b2a.x, b2a.y, b2a.z, b2a.w, b2b.x, b2b.y, b2b.z, b2b.w};
    const float4* wq = (const float4*)(Wout + tx * 16);
    float4 q0 = wq[0], q1 = wq[1], q2 = wq[2], q3 = wq[3];
    float wo0[8] = {q0.x, q0.z, q1.x, q1.z, q2.x, q2.z, q3.x, q3.z};
    float wo1[8] = {q0.y, q0.w, q1.y, q1.w, q2.y, q2.w, q3.y, q3.w};

    #pragma unroll
    for (int i = 0; i < 4; ++i) {
        float m = -1e30f;
        #pragma unroll
        for (int j = 0; j < 8; ++j) { z[i][j] += bz[j]; m = fmaxf(m, z[i][j]); }
        #pragma unroll
        for (int mk = 1; mk < 32; mk <<= 1) m = fmaxf(m, __shfl_xor(m, mk, 64));
        float s = 0.f, w0 = 0.f, w1 = 0.f;
        #pragma unroll
        for (int j = 0; j < 8; ++j) {
            float t = __expf(z[i][j] - m);
            s += t;
            w0 = fmaf(t, wo0[j], w0);
            w1 = fmaf(t, wo1[j], w1);
        }
        #pragma unroll
        for (int mk = 1; mk < 32; mk <<= 1) {
            s  += __shfl_xor(s,  mk, 64);
            w0 += __shfl_xor(w0, mk, 64);
            w1 += __shfl_xor(w1, mk, 64);
        }
        if (tx == 0) {
            int r = ty * 4 + i;
            float g = gate_s[r];
            if (g > 0.f) {
                int brow = idx_s[r];
                float inv = 1.f / s;
                atomicAdd(&out[brow * 2 + 0], g * w0 * inv);
                atomicAdd(&out[brow * 2 + 1], g * w1 * inv);
            }
        }
    }
}

extern "C" void kernel_launch(void* const* d_in, const int* in_sizes, int n_in,
                              void* d_out, int out_size, void* d_ws, size_t ws_size,
                              hipStream_t stream) {
    const float* x    = (const float*)d_in[0];
    // d_in[1] = cat_prop, unused by the reference
    const float* wg   = (const float*)d_in[2];
    const float* W1   = (const float*)d_in[3];
    const float* b1   = (const float*)d_in[4];
    const float* W2   = (const float*)d_in[5];
    const float* b2   = (const float*)d_in[6];
    const float* Wout = (const float*)d_in[7];
    const float* bout = (const float*)d_in[8];
    float* out = (float*)d_out;

    char* ws = (char*)d_ws;
    int*   gcount    = (int*)(ws + 0);
    int*   gload     = (int*)(ws + 32);
    float* gimp      = (float*)(ws + 64);
    int*   idx_list  = (int*)(ws + 128);
    float* gate_list = (float*)(ws + 128 + sizeof(int) * NE * BN);

    hipMemsetAsync(ws, 0, 128, stream);
    init_out_kernel<<<(BN * NOUT + 255) / 256, 256, 0, stream>>>(out, bout);
    gate_kernel<<<BN / 32, 256, 0, stream>>>(x, wg, gcount, gload, gimp, idx_list, gate_list);
    loss_kernel<<<1, 64, 0, stream>>>(gimp, gload, out);
    dim3 eg(BN / 32, NE);
    expert_kernel<<<eg, 256, 0, stream>>>(x, W1, b1, W2, b2, Wout,
                                          gcount, idx_list, gate_list, out);
}

// Round 2
// 337.223 us; speedup vs baseline: 1.1046x; 1.1046x over previous
//
#include <hip/hip_runtime.h>

#define BN 32768
#define IN 512
#define NE 8
#define NH 128
#define MO 256

typedef const __attribute__((address_space(1))) unsigned int gu32;
typedef __attribute__((address_space(3))) unsigned int lu32;

// async global->LDS, 16B per lane. LDS dest = wave-uniform base + lane*16,
// which our contiguous tid*16 layout satisfies.
__device__ __forceinline__ void cp16(const float* g, float* l) {
    __builtin_amdgcn_global_load_lds((gu32*)g, (lu32*)l, 16, 0, 0);
}

// ---------------- gating: logits, top-2, bucketing; fused out-init ----------
// wave-per-row batches of 8; f64 accumulation so top-2 selection matches the
// f64 np reference at near-ties (an f32 rank flip would inject ~1e-3 absmax).
__global__ __launch_bounds__(256) void gate_kernel(
    const float* __restrict__ x, const float* __restrict__ wg,
    int* __restrict__ gcount, int* __restrict__ gload, float* __restrict__ gimp,
    int* __restrict__ idx_list, float* __restrict__ gate_list,
    float* __restrict__ out, const float* __restrict__ bout)
{
    __shared__ int counts_s[NE];
    __shared__ int load_s[NE];
    __shared__ float imp_s[NE];
    __shared__ int base_s[NE];
    __shared__ int rec_e[64];
    __shared__ int rec_p[64];
    __shared__ float rec_g[64];

    int tid = threadIdx.x;
    if (tid < NE) { counts_s[tid] = 0; load_s[tid] = 0; imp_s[tid] = 0.f; }
    if (tid < 64) {  // fused init: out[row, j] = bout[j]
        int row = blockIdx.x * 32 + (tid >> 1);
        out[row * 2 + (tid & 1)] = bout[tid & 1];
    }
    __syncthreads();

    int lane = tid & 63;
    int wave = tid >> 6;

    for (int t = 0; t < 8; ++t) {
        int row = blockIdx.x * 32 + wave * 8 + t;
        const float* xr = x + (size_t)row * IN;
        double acc[NE];
        #pragma unroll
        for (int e = 0; e < NE; ++e) acc[e] = 0.0;
        #pragma unroll
        for (int j = 0; j < 8; ++j) {
            int k = lane + 64 * j;
            double xv = (double)xr[k];
            const float4* w4 = (const float4*)(wg + (size_t)k * NE);
            float4 w0 = w4[0], w1 = w4[1];
            acc[0] += xv * (double)w0.x; acc[1] += xv * (double)w0.y;
            acc[2] += xv * (double)w0.z; acc[3] += xv * (double)w0.w;
            acc[4] += xv * (double)w1.x; acc[5] += xv * (double)w1.y;
            acc[6] += xv * (double)w1.z; acc[7] += xv * (double)w1.w;
        }
        #pragma unroll
        for (int m = 1; m < 64; m <<= 1) {
            #pragma unroll
            for (int e = 0; e < NE; ++e) acc[e] += __shfl_xor(acc[e], m, 64);
        }
        if (lane == 0) {
            int e0 = 0; double v0 = acc[0];
            #pragma unroll
            for (int e = 1; e < NE; ++e) if (acc[e] > v0) { v0 = acc[e]; e0 = e; }
            int e1 = (e0 == 0) ? 1 : 0; double v1 = acc[e1];
            #pragma unroll
            for (int e = 0; e < NE; ++e)
                if (e != e0 && acc[e] > v1) { v1 = acc[e]; e1 = e; }
            float t1 = expf((float)(v1 - v0));
            float s = 1.f + t1;
            float g0 = 1.f / s;
            float g1 = t1 / s;
            atomicAdd(&imp_s[e0], g0);
            atomicAdd(&imp_s[e1], g1);
            if (g0 > 0.f) atomicAdd(&load_s[e0], 1);
            if (g1 > 0.f) atomicAdd(&load_s[e1], 1);
            int p0 = atomicAdd(&counts_s[e0], 1);
            int p1 = atomicAdd(&counts_s[e1], 1);
            int rl = (wave * 8 + t) * 2;
            rec_e[rl] = e0; rec_e[rl + 1] = e1;
            rec_g[rl] = g0; rec_g[rl + 1] = g1;
            rec_p[rl] = p0; rec_p[rl + 1] = p1;
        }
    }
    __syncthreads();
    if (tid < NE) {
        base_s[tid] = atomicAdd(&gcount[tid], counts_s[tid]);
        atomicAdd(&gimp[tid], imp_s[tid]);
        atomicAdd(&gload[tid], load_s[tid]);
    }
    __syncthreads();
    if (tid < 64) {
        int e = rec_e[tid];
        int pos = base_s[e] + rec_p[tid];
        int row = blockIdx.x * 32 + (tid >> 1);
        idx_list[e * BN + pos] = row;
        gate_list[e * BN + pos] = rec_g[tid];
    }
}

// ---------------- loss ----------------
__global__ void loss_kernel(const float* __restrict__ gimp, const int* __restrict__ gload,
                            float* __restrict__ out) {
    if (threadIdx.x == 0 && blockIdx.x == 0) {
        float mi = 0.f, ml = 0.f;
        for (int e = 0; e < NE; ++e) { mi += gimp[e]; ml += (float)gload[e]; }
        mi *= 0.125f; ml *= 0.125f;
        float vi = 0.f, vl = 0.f;
        for (int e = 0; e < NE; ++e) {
            float d = gimp[e] - mi;  vi += d * d;
            float d2 = (float)gload[e] - ml; vl += d2 * d2;
        }
        vi *= (1.f / 7.f); vl *= (1.f / 7.f);
        float loss = (vi / (mi * mi + 1e-10f) + vl / (ml * ml + 1e-10f)) * 0.01f;
        out[BN * 2] = loss;
    }
}

// ---------------- expert compute: per (expert, 32-row tile) ----------------
// All LDS arrays row-major; A-fragments read ALONG k (b128 broadcasts), so
// no transposes, no bank conflicts. W1/W2 staged via global_load_lds (each
// chunk is a contiguous 16KB copy). LDS = exactly 32KB -> 5 blocks/CU.
__global__ __launch_bounds__(256, 5) void expert_kernel(
    const float* __restrict__ x,
    const float* __restrict__ W1, const float* __restrict__ b1,
    const float* __restrict__ W2, const float* __restrict__ b2,
    const float* __restrict__ Wout,
    const int* __restrict__ gcount,
    const int* __restrict__ idx_list, const float* __restrict__ gate_list,
    float* __restrict__ out)
{
    __shared__ __align__(16) union {
        struct { float xs[32][32]; float ws1[32][128]; } s1;  // 4K + 16K
        struct { float hs[32][128]; float w2s[16][256]; } s2; // 16K + 16K = 32K
    } sm;

    int e = blockIdx.y;
    int cnt = gcount[e];
    int row0 = blockIdx.x * 32;
    if (row0 >= cnt) return;
    int tid = threadIdx.x;
    int tx = tid & 31;   // stage1 cols tx*4; stage2 cols {tx*4, 128+tx*4}
    int ty = tid >> 5;   // rows ty*4..+3

    // this thread's gathered X row for staging (8 threads per row)
    int sr = tid >> 3, sf = tid & 7;
    int sgi = row0 + sr; if (sgi >= cnt) sgi = cnt - 1;
    const float* xrow = x + (size_t)idx_list[e * BN + sgi] * IN;

    const float* W1e = W1 + (size_t)e * IN * NH;
    const float* W2e = W2 + (size_t)e * NH * MO;

    // ---- stage 1: H[32x128] = relu(X @ W1 + b1) ----
    float c1[4][4] = {};
    for (int k0 = 0; k0 < IN; k0 += 32) {
        // xs[32][32]: lanes 0..7 write 128B contiguous per row — conflict-free
        *(float4*)&sm.s1.xs[sr][sf * 4] = *(const float4*)(xrow + k0 + sf * 4);
        // ws1: contiguous 16KB from W1[k0..k0+31][:] via async DMA
        {
            const float* g = W1e + (size_t)k0 * NH;
            float* l = &sm.s1.ws1[0][0];
            #pragma unroll
            for (int p = 0; p < 4; ++p)
                cp16(g + p * 1024 + tid * 4, l + p * 1024 + tid * 4);
        }
        __syncthreads();
        #pragma unroll
        for (int q4 = 0; q4 < 8; ++q4) {
            float a[4][4], b[4][4];
            #pragma unroll
            for (int i = 0; i < 4; ++i) {
                float4 av = *(const float4*)&sm.s1.xs[ty * 4 + i][q4 * 4];
                a[i][0] = av.x; a[i][1] = av.y; a[i][2] = av.z; a[i][3] = av.w;
            }
            #pragma unroll
            for (int q = 0; q < 4; ++q) {
                float4 bv = *(const float4*)&sm.s1.ws1[q4 * 4 + q][tx * 4];
                b[q][0] = bv.x; b[q][1] = bv.y; b[q][2] = bv.z; b[q][3] = bv.w;
            }
            #pragma unroll
            for (int q = 0; q < 4; ++q)
                #pragma unroll
                for (int i = 0; i < 4; ++i)
                    #pragma unroll
                    for (int j = 0; j < 4; ++j)
                        c1[i][j] = fmaf(a[i][q], b[q][j], c1[i][j]);
        }
        __syncthreads();
    }

    // relu + b1 -> hs (row-major, contiguous float4 stores — conflict-free).
    // hs aliases xs+ws1[0..23]; all stage-1 reads completed at trailing sync.
    {
        float4 bv = *(const float4*)(b1 + e * NH + tx * 4);
        float bb[4] = {bv.x, bv.y, bv.z, bv.w};
        #pragma unroll
        for (int i = 0; i < 4; ++i) {
            float4 h;
            h.x = fmaxf(c1[i][0] + bb[0], 0.f);
            h.y = fmaxf(c1[i][1] + bb[1], 0.f);
            h.z = fmaxf(c1[i][2] + bb[2], 0.f);
            h.w = fmaxf(c1[i][3] + bb[3], 0.f);
            *(float4*)&sm.s2.hs[ty * 4 + i][tx * 4] = h;
        }
    }

    // ---- stage 2: Z[32x256] = H @ W2 ----
    float z[4][8] = {};
    for (int k0 = 0; k0 < NH; k0 += 16) {
        {
            const float* g = W2e + (size_t)k0 * MO;
            float* l = &sm.s2.w2s[0][0];
            #pragma unroll
            for (int p = 0; p < 4; ++p)
                cp16(g + p * 1024 + tid * 4, l + p * 1024 + tid * 4);
        }
        __syncthreads();  // covers hs stores (first iter) + w2s DMA
        #pragma unroll
        for (int q4 = 0; q4 < 4; ++q4) {
            float a[4][4];
            #pragma unroll
            for (int i = 0; i < 4; ++i) {
                float4 av = *(const float4*)&sm.s2.hs[ty * 4 + i][k0 + q4 * 4];
                a[i][0] = av.x; a[i][1] = av.y; a[i][2] = av.z; a[i][3] = av.w;
            }
            #pragma unroll
            for (int q = 0; q < 4; ++q) {
                float4 blo = *(const float4*)&sm.s2.w2s[q4 * 4 + q][tx * 4];
                float4 bhi = *(const float4*)&sm.s2.w2s[q4 * 4 + q][128 + tx * 4];
                float bl[4] = {blo.x, blo.y, blo.z, blo.w};
                float bh[4] = {bhi.x, bhi.y, bhi.z, bhi.w};
                #pragma unroll
                for (int i = 0; i < 4; ++i)
                    #pragma unroll
                    for (int j = 0; j < 4; ++j) {
                        z[i][j]     = fmaf(a[i][q], bl[j], z[i][j]);
                        z[i][j + 4] = fmaf(a[i][q], bh[j], z[i][j + 4]);
                    }
            }
        }
        __syncthreads();
    }

    // ---- epilogue: softmax over 256 cols (32 lanes x 8), fused @Wout ----
    // thread's cols: j<4 -> tx*4+j ; j>=4 -> 128+tx*4+(j-4)
    float4 b2a = *(const float4*)(b2 + e * MO + tx * 4);
    float4 b2b = *(const float4*)(b2 + e * MO + 128 + tx * 4);
    float bz[8] = {b2a.x, b2a.y, b2a.z, b2a.w, b2b.x, b2b.y, b2b.z, b2b.w};
    float4 wa0 = *(const float4*)(Wout + tx * 8);
    float4 wa1 = *(const float4*)(Wout + tx * 8 + 4);
    float4 wb0 = *(const float4*)(Wout + 256 + tx * 8);
    float4 wb1 = *(const float4*)(Wout + 256 + tx * 8 + 4);
    float wo0[8] = {wa0.x, wa0.z, wa1.x, wa1.z, wb0.x, wb0.z, wb1.x, wb1.z};
    float wo1[8] = {wa0.y, wa0.w, wa1.y, wa1.w, wb0.y, wb0.w, wb1.y, wb1.w};

    #pragma unroll
    for (int i = 0; i < 4; ++i) {
        float m = -1e30f;
        #pragma unroll
        for (int j = 0; j < 8; ++j) { z[i][j] += bz[j]; m = fmaxf(m, z[i][j]); }
        #pragma unroll
        for (int mk = 1; mk < 32; mk <<= 1) m = fmaxf(m, __shfl_xor(m, mk, 64));
        float s = 0.f, w0 = 0.f, w1 = 0.f;
        #pragma unroll
        for (int j = 0; j < 8; ++j) {
            float t = __expf(z[i][j] - m);
            s += t;
            w0 = fmaf(t, wo0[j], w0);
            w1 = fmaf(t, wo1[j], w1);
        }
        #pragma unroll
        for (int mk = 1; mk < 32; mk <<= 1) {
            s  += __shfl_xor(s,  mk, 64);
            w0 += __shfl_xor(w0, mk, 64);
            w1 += __shfl_xor(w1, mk, 64);
        }
        if (tx == 0) {
            int gi = row0 + ty * 4 + i;
            if (gi < cnt) {
                float g = gate_list[e * BN + gi];
                int brow = idx_list[e * BN + gi];
                float inv = 1.f / s;
                atomicAdd(&out[brow * 2 + 0], g * w0 * inv);
                atomicAdd(&out[brow * 2 + 1], g * w1 * inv);
            }
        }
    }
}

extern "C" void kernel_launch(void* const* d_in, const int* in_sizes, int n_in,
                              void* d_out, int out_size, void* d_ws, size_t ws_size,
                              hipStream_t stream) {
    const float* x    = (const float*)d_in[0];
    // d_in[1] = cat_prop, unused by the reference
    const float* wg   = (const float*)d_in[2];
    const float* W1   = (const float*)d_in[3];
    const float* b1   = (const float*)d_in[4];
    const float* W2   = (const float*)d_in[5];
    const float* b2   = (const float*)d_in[6];
    const float* Wout = (const float*)d_in[7];
    const float* bout = (const float*)d_in[8];
    float* out = (float*)d_out;

    char* ws = (char*)d_ws;
    int*   gcount    = (int*)(ws + 0);
    int*   gload     = (int*)(ws + 32);
    float* gimp      = (float*)(ws + 64);
    int*   idx_list  = (int*)(ws + 128);
    float* gate_list = (float*)(ws + 128 + sizeof(int) * NE * BN);

    hipMemsetAsync(ws, 0, 128, stream);
    gate_kernel<<<BN / 32, 256, 0, stream>>>(x, wg, gcount, gload, gimp,
                                             idx_list, gate_list, out, bout);
    loss_kernel<<<1, 64, 0, stream>>>(gimp, gload, out);
    dim3 eg(BN / 32, NE);
    expert_kernel<<<eg, 256, 0, stream>>>(x, W1, b1, W2, b2, Wout,
                                          gcount, idx_list, gate_list, out);
}